// Round 1
// baseline (174.266 us; speedup 1.0000x reference)
//
#include <hip/hip_runtime.h>
#include <stdint.h>

#define S      56
#define NC     20
#define NBX    2
#define NCELL  (S*S)          // 3136
#define NBOXES (NCELL*NBX)    // 6272
#define DIM    94080          // NCELL*NC + NCELL*NBX + NCELL*NBX*4
#define BD1    62720          // NCELL*NC
#define BD2    68992          // BD1 + NCELL*NBX
#define CAND   256
#define MAXOUT 30
#define NTHR   256

__device__ __forceinline__ uint64_t make_key(uint32_t sb, int idx) {
    // higher score -> higher key; equal score -> lower idx -> higher key
    return ((uint64_t)sb << 13) | (uint64_t)(8191 - idx);
}

__global__ __launch_bounds__(NTHR) void det_kernel(const float* __restrict__ in,
                                                   float* __restrict__ out) {
#pragma clang fp contract(off)
    const int b    = blockIdx.x;
    const int tid  = threadIdx.x;
    const int lane = tid & 63;
    const int wid  = tid >> 6;
    const float* img = in + (size_t)b * DIM;

    __shared__ uint32_t sbits[NBOXES];        // score bits (>=0 floats: uint order == float order)
    __shared__ uint8_t  cls8[NBOXES];
    __shared__ uint32_t hist[256];
    __shared__ uint32_t wsum[4];
    __shared__ uint64_t sel_prefix;
    __shared__ int      sel_rank;
    __shared__ uint64_t skey[CAND];
    __shared__ int      nsel;
    __shared__ float cymin[CAND], cxmin[CAND], cymax[CAND], cxmax[CAND];
    __shared__ float carea[CAND], cscore[CAND], ccls[CAND];
    __shared__ unsigned long long ball[4];
    __shared__ int pick_s;
    __shared__ int klist[MAXOUT];
    __shared__ float rowbuf[MAXOUT * 6];

    // ---------- Phase 1: per-cell score decode ----------
    for (int cell = tid; cell < NCELL; cell += NTHR) {
        const float4* pv = (const float4*)(img + cell * NC);
        float p[NC];
        #pragma unroll
        for (int q = 0; q < 5; q++) {
            float4 v = pv[q];
            p[4*q+0] = v.x; p[4*q+1] = v.y; p[4*q+2] = v.z; p[4*q+3] = v.w;
        }
        float2 cf = *(const float2*)(img + BD1 + cell * 2);
        #pragma unroll
        for (int bb = 0; bb < NBX; bb++) {
            float conf = bb ? cf.y : cf.x;
            float best = conf * p[0];   // rn multiply; max over rounded products == rn(conf*max p)
            int   cls  = 0;
            #pragma unroll
            for (int c = 1; c < NC; c++) {
                float v = conf * p[c];  // per-product argmax: first-occurrence on rounded ties
                if (v > best) { best = v; cls = c; }
            }
            float s = (best >= 0.1f) ? best : 0.0f;
            int idx = cell * 2 + bb;
            sbits[idx] = __float_as_uint(s);
            cls8[idx]  = (uint8_t)cls;
        }
    }
    if (tid == 0) nsel = 0;
    __syncthreads();

    // ---------- Phase 2: radix-select the exact rank-256 key ----------
    uint64_t prefix = 0;
    int      rank   = CAND;
    for (int pass = 0; pass < 6; pass++) {
        const int shift = 40 - 8 * pass;
        hist[tid] = 0;
        __syncthreads();
        for (int idx = tid; idx < NBOXES; idx += NTHR) {
            uint64_t key = make_key(sbits[idx], idx);
            if ((key >> (shift + 8)) == prefix)
                atomicAdd(&hist[(uint32_t)(key >> shift) & 255u], 1u);
        }
        __syncthreads();
        uint32_t mycount = hist[tid];
        // inclusive suffix-sum across 256 bins: wave shuffle + cross-wave fixup
        uint32_t v = mycount;
        #pragma unroll
        for (int off = 1; off < 64; off <<= 1) {
            uint32_t u = __shfl_down(v, off);
            if (lane + off < 64) v += u;
        }
        if (lane == 0) wsum[wid] = v;
        __syncthreads();
        uint32_t add = 0;
        for (int w = wid + 1; w < 4; w++) add += wsum[w];
        uint32_t suf    = v + add;        // count of keys with bucket >= tid under prefix
        uint32_t cnt_gt = suf - mycount;  // strictly greater buckets
        if ((int)cnt_gt < rank && rank <= (int)suf) {
            sel_prefix = (prefix << 8) | (uint64_t)tid;
            sel_rank   = rank - (int)cnt_gt;
        }
        __syncthreads();
        prefix = sel_prefix;
        rank   = sel_rank;
        __syncthreads();
    }
    const uint64_t K256 = prefix;  // exact key of the 256th-largest element

    // ---------- Phase 3: compact the 256 selected keys, bitonic sort descending ----------
    for (int idx = tid; idx < NBOXES; idx += NTHR) {
        uint64_t key = make_key(sbits[idx], idx);
        if (key >= K256) {
            int p = atomicAdd(&nsel, 1);
            if (p < CAND) skey[p] = key;
        }
    }
    __syncthreads();
    for (int k = 2; k <= CAND; k <<= 1) {
        for (int j = k >> 1; j > 0; j >>= 1) {
            int ixj = tid ^ j;
            if (ixj > tid) {
                uint64_t a = skey[tid], c = skey[ixj];
                bool up = ((tid & k) == 0);
                if (up ? (a < c) : (a > c)) { skey[tid] = c; skey[ixj] = a; }
            }
            __syncthreads();
        }
    }

    // ---------- Phase 4: decode candidate boxes (contract(off) to match np rounding) ----------
    {
        uint64_t key = skey[tid];
        int idx      = 8191 - (int)(key & 0x1FFF);
        uint32_t sb  = (uint32_t)(key >> 13);
        int cell = idx >> 1, bb = idx & 1;
        int i = cell / S, j = cell - i * S;   // i = row (y), j = col (x)
        float4 co = *(const float4*)(img + BD2 + cell * 8 + bb * 4);
        float x  = (co.x + (float)j) / 56.0f;
        float y  = (co.y + (float)i) / 56.0f;
        float wx = co.z * co.z;
        float wy = co.w * co.w;
        float hx = wx * 0.5f, hy = wy * 0.5f;
        float xmin = x - hx, ymin = y - hy, xmax = x + hx, ymax = y + hy;
        cymin[tid] = ymin; cxmin[tid] = xmin; cymax[tid] = ymax; cxmax[tid] = xmax;
        carea[tid] = fmaxf(ymax - ymin, 0.0f) * fmaxf(xmax - xmin, 0.0f);
        cscore[tid] = __uint_as_float(sb);
        ccls[tid]   = (float)cls8[idx];
    }
    if (tid < MAXOUT) klist[tid] = -1;
    __syncthreads();

    // ---------- Phase 5: greedy NMS (sorted order -> pick first valid) ----------
    bool  myvalid = true;
    float my_ymin = cymin[tid], my_xmin = cxmin[tid];
    float my_ymax = cymax[tid], my_xmax = cxmax[tid];
    float my_area = carea[tid];
    for (int it = 0; it < MAXOUT; it++) {
        unsigned long long bl = __ballot(myvalid);
        if (lane == 0) ball[wid] = bl;
        __syncthreads();
        if (tid == 0) {
            int p = -1;
            #pragma unroll
            for (int w = 0; w < 4; w++)
                if (p < 0 && ball[w]) p = w * 64 + (__ffsll(ball[w]) - 1);
            pick_s = p;
            if (p >= 0) klist[it] = p;
        }
        __syncthreads();
        int p = pick_s;
        if (p < 0) break;
        float iy = fmaxf(0.0f, fminf(cymax[p], my_ymax) - fmaxf(cymin[p], my_ymin));
        float ix = fmaxf(0.0f, fminf(cxmax[p], my_xmax) - fmaxf(cxmin[p], my_xmin));
        float inter = iy * ix;
        float uni   = carea[p] + my_area - inter;
        float iou   = (uni > 0.0f) ? (inter / uni) : 0.0f;
        if (!(iou <= 0.4f) || tid == p) myvalid = false;
    }
    __syncthreads();

    // ---------- Phase 6: emit 30x6 rows (picks in order, zero-padded) ----------
    if (tid < MAXOUT) {
        int p = klist[tid];
        float* r = &rowbuf[tid * 6];
        if (p >= 0) {
            r[0] = cymin[p]; r[1] = cxmin[p]; r[2] = cymax[p];
            r[3] = cxmax[p]; r[4] = cscore[p]; r[5] = ccls[p];
        } else {
            r[0] = r[1] = r[2] = r[3] = r[4] = r[5] = 0.0f;
        }
    }
    __syncthreads();
    float* ob = out + (size_t)b * (MAXOUT * 6);
    if (tid < MAXOUT * 6) ob[tid] = rowbuf[tid];
}

extern "C" void kernel_launch(void* const* d_in, const int* in_sizes, int n_in,
                              void* d_out, int out_size, void* d_ws, size_t ws_size,
                              hipStream_t stream) {
    const float* in  = (const float*)d_in[0];
    float*       out = (float*)d_out;
    const int B = in_sizes[0] / DIM;   // 256
    det_kernel<<<dim3(B), dim3(NTHR), 0, stream>>>(in, out);
}

// Round 2
// 164.170 us; speedup vs baseline: 1.0615x; 1.0615x over previous
//
#include <hip/hip_runtime.h>
#include <stdint.h>

#define S      56
#define NC     20
#define NBX    2
#define NCELL  (S*S)          // 3136
#define NBOXES (NCELL*NBX)    // 6272
#define DIM    94080          // NCELL*NC + NCELL*NBX + NCELL*NBX*4
#define BD1    62720          // NCELL*NC
#define BD2    68992          // BD1 + NCELL*NBX
#define CAND   256
#define MAXOUT 30
#define NTHR   1024
#define NWAVE  (NTHR/64)      // 16

__device__ __forceinline__ uint64_t make_key(uint32_t sb, int idx) {
    // higher score -> higher key; equal score -> lower idx -> higher key
    return ((uint64_t)sb << 13) | (uint64_t)(8191 - idx);
}

__global__ __launch_bounds__(NTHR) void det_kernel(const float* __restrict__ in,
                                                   float* __restrict__ out) {
#pragma clang fp contract(off)
    const int b    = blockIdx.x;
    const int tid  = threadIdx.x;
    const int lane = tid & 63;
    const int wv   = tid >> 6;    // 0..15
    const float* img = in + (size_t)b * DIM;

    __shared__ uint32_t sbits[NBOXES];                      // 25088 B
    __shared__ uint8_t  cls8[NBOXES];                       //  6272 B
    __shared__ __attribute__((aligned(16))) uint32_t hist[NWAVE][256]; // 16384 B
    __shared__ uint64_t skey[CAND];                         //  2048 B
    __shared__ uint64_t ssort[CAND];                        //  2048 B
    __shared__ uint64_t sel_prefix;
    __shared__ uint32_t sel_rank;
    __shared__ int      nsel;
    __shared__ float cymin[CAND], cxmin[CAND], cymax[CAND], cxmax[CAND];
    __shared__ float carea[CAND], cscore[CAND], ccls[CAND]; //  7168 B
    __shared__ int   klist[MAXOUT];
    __shared__ float rowbuf[MAXOUT * 6];

    // ---------- Phase 1: per-cell score decode (16 waves hide L3 latency) ----------
    for (int cell = tid; cell < NCELL; cell += NTHR) {
        const float4* pv = (const float4*)(img + cell * NC);
        float p[NC];
        #pragma unroll
        for (int q = 0; q < 5; q++) {
            float4 v = pv[q];
            p[4*q+0] = v.x; p[4*q+1] = v.y; p[4*q+2] = v.z; p[4*q+3] = v.w;
        }
        float2 cf = *(const float2*)(img + BD1 + cell * 2);
        #pragma unroll
        for (int bb = 0; bb < NBX; bb++) {
            float conf = bb ? cf.y : cf.x;
            float best = conf * p[0];   // rn multiply; first-occurrence argmax on rounded products
            int   cls  = 0;
            #pragma unroll
            for (int c = 1; c < NC; c++) {
                float v = conf * p[c];
                if (v > best) { best = v; cls = c; }
            }
            float s = (best >= 0.1f) ? best : 0.0f;
            int idx = cell * 2 + bb;
            sbits[idx] = __float_as_uint(s);
            cls8[idx]  = (uint8_t)cls;
        }
    }
    if (tid == 0) nsel = 0;
    __syncthreads();

    // ---------- Phase 2: radix-select exact rank-256 key (45-bit, 6x8-bit passes) ----------
    uint64_t prefix = 0;
    uint32_t rank   = CAND;
    for (int pass = 0; pass < 6; pass++) {
        const int shift = 40 - 8 * pass;
        // zero per-wave histograms
        for (int i = tid; i < NWAVE * 256; i += NTHR) ((uint32_t*)hist)[i] = 0;
        __syncthreads();
        for (int idx = tid; idx < NBOXES; idx += NTHR) {
            uint64_t key = make_key(sbits[idx], idx);
            if ((key >> (shift + 8)) == prefix)
                atomicAdd(&hist[wv][(uint32_t)(key >> shift) & 255u], 1u);
        }
        __syncthreads();
        if (wv == 0) {
            // lane handles bins 4*lane .. 4*lane+3 (descending-digit suffix sums)
            uint32_t c0 = 0, c1 = 0, c2 = 0, c3 = 0;
            #pragma unroll
            for (int w = 0; w < NWAVE; w++) {
                uint4 h = ((const uint4*)hist[w])[lane];
                c0 += h.x; c1 += h.y; c2 += h.z; c3 += h.w;
            }
            uint32_t t = c0 + c1 + c2 + c3;
            uint32_t v = t;
            #pragma unroll
            for (int off = 1; off < 64; off <<= 1) {
                uint32_t u = __shfl_down(v, off);
                if (lane + off < 64) v += u;
            }
            uint32_t above = v - t;          // keys in strictly-higher lanes' bins
            uint32_t s3 = above + c3;        // inclusive suffix per bin
            uint32_t s2 = s3 + c2;
            uint32_t s1 = s2 + c1;
            uint32_t s0 = s1 + c0;
            int dsel = -1; uint32_t g = 0;
            if      (above < rank && rank <= s3) { dsel = 4*lane+3; g = above; }
            else if (s3    < rank && rank <= s2) { dsel = 4*lane+2; g = s3; }
            else if (s2    < rank && rank <= s1) { dsel = 4*lane+1; g = s2; }
            else if (s1    < rank && rank <= s0) { dsel = 4*lane+0; g = s1; }
            if (dsel >= 0) {                 // exactly one lane hits
                sel_prefix = (prefix << 8) | (uint64_t)dsel;
                sel_rank   = rank - g;
            }
        }
        __syncthreads();
        prefix = sel_prefix;
        rank   = sel_rank;
    }
    const uint64_t K256 = prefix;  // exact 256th-largest key

    // ---------- Phase 3: compact the 256 selected keys ----------
    for (int idx = tid; idx < NBOXES; idx += NTHR) {
        uint64_t key = make_key(sbits[idx], idx);
        if (key >= K256) {
            int p = atomicAdd(&nsel, 1);
            if (p < CAND) skey[p] = key;
        }
    }
    if (tid < MAXOUT) klist[tid] = -1;
    __syncthreads();

    // ---------- Phase 4: O(n^2) rank sort (keys unique) + candidate box decode ----------
    if (tid < CAND) {
        uint64_t my = skey[tid];
        int r = 0;
        #pragma unroll 8
        for (int j = 0; j < CAND; j++) r += (skey[j] > my);  // broadcast LDS reads
        ssort[r] = my;
    }
    __syncthreads();
    if (tid < CAND) {
        uint64_t key = ssort[tid];
        int idx      = 8191 - (int)(key & 0x1FFF);
        uint32_t sb  = (uint32_t)(key >> 13);
        int cell = idx >> 1, bb = idx & 1;
        int i = cell / S, j = cell - i * S;   // i = row (y), j = col (x)
        float4 co = *(const float4*)(img + BD2 + cell * 8 + bb * 4);
        float x  = (co.x + (float)j) / 56.0f;
        float y  = (co.y + (float)i) / 56.0f;
        float wx = co.z * co.z;
        float wy = co.w * co.w;
        float hx = wx * 0.5f, hy = wy * 0.5f;
        float xmin = x - hx, ymin = y - hy, xmax = x + hx, ymax = y + hy;
        cymin[tid] = ymin; cxmin[tid] = xmin; cymax[tid] = ymax; cxmax[tid] = xmax;
        carea[tid] = fmaxf(ymax - ymin, 0.0f) * fmaxf(xmax - xmin, 0.0f);
        cscore[tid] = __uint_as_float(sb);
        ccls[tid]   = (float)cls8[idx];
    }
    __syncthreads();

    // ---------- Phase 5: single-wave greedy NMS (no barriers inside) ----------
    if (wv == 0) {
        float bym[4], bxm[4], byM[4], bxM[4], bar[4];
        #pragma unroll
        for (int s = 0; s < 4; s++) {
            int c = lane + 64 * s;
            bym[s] = cymin[c]; bxm[s] = cxmin[c];
            byM[s] = cymax[c]; bxM[s] = cxmax[c]; bar[s] = carea[c];
        }
        unsigned valid = 0xFu;   // bit s = candidate (lane + 64*s) still valid
        for (int it = 0; it < MAXOUT; it++) {
            int p = -1;
            #pragma unroll
            for (int s = 0; s < 4; s++) {
                if (p < 0) {
                    unsigned long long bl = __ballot((valid >> s) & 1u);
                    if (bl) p = 64 * s + (__ffsll(bl) - 1);   // wave-uniform
                }
            }
            if (p < 0) break;                                  // uniform
            if (lane == 0) klist[it] = p;
            float pym = cymin[p], pxm = cxmin[p];
            float pyM = cymax[p], pxM = cxmax[p], par = carea[p];
            #pragma unroll
            for (int s = 0; s < 4; s++) {
                int c = lane + 64 * s;
                float iy = fmaxf(0.0f, fminf(pyM, byM[s]) - fmaxf(pym, bym[s]));
                float ix = fmaxf(0.0f, fminf(pxM, bxM[s]) - fmaxf(pxm, bxm[s]));
                float inter = iy * ix;
                float uni   = par + bar[s] - inter;
                float iou   = (uni > 0.0f) ? (inter / uni) : 0.0f;  // exact div: matches np rounding
                if (c == p || !(iou <= 0.4f)) valid &= ~(1u << s);
            }
        }
    }
    __syncthreads();

    // ---------- Phase 6: emit 30x6 rows (picks in order, zero-padded) ----------
    if (tid < MAXOUT) {
        int p = klist[tid];
        float* r = &rowbuf[tid * 6];
        if (p >= 0) {
            r[0] = cymin[p]; r[1] = cxmin[p]; r[2] = cymax[p];
            r[3] = cxmax[p]; r[4] = cscore[p]; r[5] = ccls[p];
        } else {
            r[0] = r[1] = r[2] = r[3] = r[4] = r[5] = 0.0f;
        }
    }
    __syncthreads();
    float* ob = out + (size_t)b * (MAXOUT * 6);
    if (tid < MAXOUT * 6) ob[tid] = rowbuf[tid];
}

extern "C" void kernel_launch(void* const* d_in, const int* in_sizes, int n_in,
                              void* d_out, int out_size, void* d_ws, size_t ws_size,
                              hipStream_t stream) {
    const float* in  = (const float*)d_in[0];
    float*       out = (float*)d_out;
    const int B = in_sizes[0] / DIM;   // 256
    det_kernel<<<dim3(B), dim3(NTHR), 0, stream>>>(in, out);
}